// Round 1
// 287.592 us; speedup vs baseline: 1.0612x; 1.0612x over previous
//
#include <hip/hip_runtime.h>

typedef __bf16 bf16x8 __attribute__((ext_vector_type(8)));
typedef float f32x4 __attribute__((ext_vector_type(4)));
typedef unsigned short u16;
typedef unsigned short u16x4 __attribute__((ext_vector_type(4)));
typedef unsigned short u16x8 __attribute__((ext_vector_type(8)));
typedef unsigned int u32x2 __attribute__((ext_vector_type(2)));

#define DEVFN __device__ __forceinline__

DEVFN u16 f32_to_bf16(float f) {
  unsigned int u = __float_as_uint(f);
  u += 0x7FFFu + ((u >> 16) & 1u);   // round-to-nearest-even
  return (u16)(u >> 16);
}

// pack two f32 -> u32 of 2 bf16 (low = a, high = b), single VALU op
DEVFN unsigned int cvt_pk_bf16(float a, float b) {
  unsigned int r;
  asm("v_cvt_pk_bf16_f32 %0, %1, %2" : "=v"(r) : "v"(a), "v"(b));
  return r;
}

DEVFN void load_lds16(const void* g, void* l) {
  __builtin_amdgcn_global_load_lds(
      (__attribute__((address_space(1))) void*)g,
      (__attribute__((address_space(3))) void*)l,
      16, 0, 0);
}

// ---------------------------------------------------------------------------
// prep: c -> bf16 stream; q -> [B,H,S,64] bf16 pre-scaled by 0.125*log2(e)
// ---------------------------------------------------------------------------
__global__ void cvt_cq_kernel(const float* __restrict__ c, const float* __restrict__ q,
                              u16* __restrict__ c_bf, u16* __restrict__ qh) {
  const int bid = blockIdx.x;
  if (bid < 4096) {
    int i = bid * 256 + threadIdx.x;
    const float4* p = (const float4*)c + (size_t)i * 2;
    float4 a = p[0], b = p[1];
    u16x8 o;
    o[0] = f32_to_bf16(a.x); o[1] = f32_to_bf16(a.y);
    o[2] = f32_to_bf16(a.z); o[3] = f32_to_bf16(a.w);
    o[4] = f32_to_bf16(b.x); o[5] = f32_to_bf16(b.y);
    o[6] = f32_to_bf16(b.z); o[7] = f32_to_bf16(b.w);
    *(u16x8*)(c_bf + (size_t)i * 8) = o;
  } else {
    const float SC = 0.125f * 1.44269504088896f;
    int i = (bid - 4096) * 256 + threadIdx.x;
    int dc = i & 7, sx = (i >> 3) & 2047, h = (i >> 14) & 15, b = i >> 18;
    const float4* p = (const float4*)(q + ((size_t)(b * 2048 + sx)) * 1024 + h * 64 + dc * 8);
    float4 a = p[0], bb = p[1];
    u16x8 o;
    o[0] = f32_to_bf16(a.x * SC);  o[1] = f32_to_bf16(a.y * SC);
    o[2] = f32_to_bf16(a.z * SC);  o[3] = f32_to_bf16(a.w * SC);
    o[4] = f32_to_bf16(bb.x * SC); o[5] = f32_to_bf16(bb.y * SC);
    o[6] = f32_to_bf16(bb.z * SC); o[7] = f32_to_bf16(bb.w * SC);
    *(u16x8*)(qh + (size_t)i * 8) = o;
  }
}

// W [1024][N] f32 -> Wt [N][1024] bf16 (64x64 LDS tile transpose)
__global__ void transpose_w_kernel(const float* __restrict__ in, u16* __restrict__ out, int N) {
  __shared__ __align__(16) u16 T[64 * 72];
  const int tid = threadIdx.x;
  const int n0 = blockIdx.x * 64, k0 = blockIdx.y * 64;
#pragma unroll
  for (int p = 0; p < 4; ++p) {
    int l = p * 256 + tid;
    int k = l >> 4, nc = l & 15;
    const float4 v = *(const float4*)(in + (size_t)(k0 + k) * N + n0 + nc * 4);
    T[(nc * 4 + 0) * 72 + k] = f32_to_bf16(v.x);
    T[(nc * 4 + 1) * 72 + k] = f32_to_bf16(v.y);
    T[(nc * 4 + 2) * 72 + k] = f32_to_bf16(v.z);
    T[(nc * 4 + 3) * 72 + k] = f32_to_bf16(v.w);
  }
  __syncthreads();
#pragma unroll
  for (int p = 0; p < 2; ++p) {
    int u = p * 256 + tid;
    int n = u >> 3, kc = u & 7;
    u16x8 o = *(const u16x8*)(T + n * 72 + kc * 8);
    *(u16x8*)(out + (size_t)(n0 + n) * 1024 + k0 + kc * 8) = o;
  }
}

// ---------------------------------------------------------------------------
// 128x128 bf16 GEMM, BK=64, global_load_lds + XOR-swizzled LDS
// MODE 0: KV epilogue — K scattered per head; V transposed via LDS and
//         written directly as Vt [bh][64 d][2048 sx] (kills transpose_v).
// MODE 1: fp32 out (O-proj).
// ---------------------------------------------------------------------------
template <int MODE>
__global__ __launch_bounds__(256, 2) void gemm128(
    const u16* __restrict__ A, const u16* __restrict__ Bt,
    const float* __restrict__ bias,
    u16* __restrict__ outK, u16* __restrict__ outV,
    float* __restrict__ outF, int K) {
  __shared__ __align__(16) u16 SMEM[2 * 128 * 64];   // As | Bs ; reused as VT
  u16* As = SMEM;
  u16* Bs = SMEM + 128 * 64;
  const int tid = threadIdx.x;
  const int lane = tid & 63, w = tid >> 6, quad = lane >> 4, l15 = lane & 15;
  const int wm = w & 1, wn = w >> 1;
  const int tn = blockIdx.x, tm = blockIdx.y;
  const u16* Ab = A + (size_t)tm * 128 * K;
  const u16* Bb = Bt + (size_t)tn * 128 * K;

  const f32x4 zero4 = {0.f, 0.f, 0.f, 0.f};
  f32x4 acc[4][4];
#pragma unroll
  for (int mi = 0; mi < 4; ++mi)
#pragma unroll
    for (int ni = 0; ni < 4; ++ni) acc[mi][ni] = zero4;

  for (int k0 = 0; k0 < K; k0 += 64) {
#pragma unroll
    for (int p = 0; p < 4; ++p) {
      int l = p * 256 + tid;
      int r = l >> 3, dc = l & 7;
      int go = r * K + k0 + ((dc ^ (r & 7)) * 8);
      int lb = (p * 256 + (tid & 192)) * 8;
      load_lds16(Ab + go, As + lb);
      load_lds16(Bb + go, Bs + lb);
    }
    __syncthreads();
#pragma unroll
    for (int kk = 0; kk < 2; ++kk) {
      bf16x8 av[4], bv[4];
#pragma unroll
      for (int i = 0; i < 4; ++i) {
        int sw = ((kk * 4 + quad) ^ (l15 & 7)) * 8;
        av[i] = *(const bf16x8*)(As + (wm * 64 + i * 16 + l15) * 64 + sw);
        bv[i] = *(const bf16x8*)(Bs + (wn * 64 + i * 16 + l15) * 64 + sw);
      }
#pragma unroll
      for (int mi = 0; mi < 4; ++mi)
#pragma unroll
        for (int ni = 0; ni < 4; ++ni)
          acc[mi][ni] = __builtin_amdgcn_mfma_f32_16x16x32_bf16(av[mi], bv[ni], acc[mi][ni], 0, 0, 0);
    }
    __syncthreads();
  }

  if (MODE == 0) {
    // n = tn*128 + wn*64 + ni*16 + l15 ; head h = tn ; rr = wn*64 + ni*16 + l15
    // wn==0 -> K half (rr<64), wn==1 -> V half (rr>=64, d = rr-64)
    const int h = tn;
    const int b = tm >> 4;
    const int sx0 = (tm & 15) * 128;
    u16* VT = SMEM;   // [64 d][128 sx] stride 136 — As/Bs dead after final sync
    if (wn == 0) {
#pragma unroll
      for (int ni = 0; ni < 4; ++ni) {
        const int d = ni * 16 + l15;
        const float bb = bias[tn * 128 + d];
#pragma unroll
        for (int mi = 0; mi < 4; ++mi) {
#pragma unroll
          for (int r = 0; r < 4; ++r) {
            const int sx = sx0 + wm * 64 + mi * 16 + quad * 4 + r;
            outK[((size_t)(b * 16 + h) * 2048 + sx) * 64 + d] = f32_to_bf16(acc[mi][ni][r] + bb);
          }
        }
      }
    } else {
#pragma unroll
      for (int ni = 0; ni < 4; ++ni) {
        const int d = ni * 16 + l15;
        const float bb = bias[tn * 128 + 64 + d];
#pragma unroll
        for (int mi = 0; mi < 4; ++mi) {
          u16x4 pk;
#pragma unroll
          for (int r = 0; r < 4; ++r) pk[r] = f32_to_bf16(acc[mi][ni][r] + bb);
          *(u16x4*)(VT + d * 136 + wm * 64 + mi * 16 + quad * 4) = pk;
        }
      }
    }
    __syncthreads();
    // cooperative coalesced store of VT -> outV [bh][d][sx]
    {
      const int d = tid >> 2, ch = tid & 3;
      u16* dst = outV + (((size_t)(b * 16 + h) * 64 + d) * 2048 + sx0 + ch * 32);
      const u16* src = VT + d * 136 + ch * 32;
#pragma unroll
      for (int i = 0; i < 4; ++i)
        *(u16x8*)(dst + i * 8) = *(const u16x8*)(src + i * 8);
    }
  } else {
#pragma unroll
    for (int ni = 0; ni < 4; ++ni) {
      const int n = tn * 128 + wn * 64 + ni * 16 + l15;
      const float bb = bias[n];
#pragma unroll
      for (int mi = 0; mi < 4; ++mi) {
#pragma unroll
        for (int r = 0; r < 4; ++r) {
          const int m = tm * 128 + wm * 64 + mi * 16 + quad * 4 + r;
          outF[(size_t)m * 1024 + n] = acc[mi][ni][r] + bb;
        }
      }
    }
  }
}

// ---------------------------------------------------------------------------
// flash attention v4: 64-q-row blocks (1 wave = 16 q rows), 2048 blocks.
// S^T = K·Q^T, no online max (logits bounded), deferred l-reduction.
// P never touches LDS: exp2 -> v_cvt_pk_bf16_f32 -> permlane32/16_swap
// redistributes kv across quads in-register (q is already lane-local, q=l15
// in both the S^T C-layout and the PV A-fragment layout).
// LDS = Ks+Vts = exactly 32 KB -> 5 blocks/CU.
// ---------------------------------------------------------------------------
__global__ __launch_bounds__(256, 5) void flash_kernel(
    const u16* __restrict__ Qh,   // [BH,2048,64] bf16, pre-scaled
    const u16* __restrict__ Kp,   // [BH,2048,64]
    const u16* __restrict__ Vt,   // [BH,64,2048]
    u16* __restrict__ Opk) {      // [B,2048,1024] bf16
  __shared__ __align__(16) u16 Ks[128 * 64];
  __shared__ __align__(16) u16 Vts[64 * 128];

  const int tid = threadIdx.x;
  const int lane = tid & 63, w = tid >> 6, quad = lane >> 4, l15 = lane & 15;
  // XCD-swizzled mapping: same bh stays on one XCD (L2 K/V reuse)
  const int id = blockIdx.x;
  const int bh = (id & 7) + 8 * (id >> 8);
  const int qt = (id >> 3) & 31;
  const int q0 = qt * 64;

  const u16* kbase = Kp + (size_t)bh * 2048 * 64;
  const u16* vbase = Vt + (size_t)bh * 64 * 2048;

  // Q B-fragments straight from global: B[n=q][k=d], n=l15, k=quad*8+j
  const u16* qrow = Qh + ((size_t)bh * 2048 + q0 + w * 16 + l15) * 64;
  bf16x8 bq0 = *(const bf16x8*)(qrow + quad * 8);
  bf16x8 bq1 = *(const bf16x8*)(qrow + 32 + quad * 8);

  const f32x4 zero4 = {0.f, 0.f, 0.f, 0.f};
  f32x4 oacc[4];
  f32x4 lsumv = zero4;
#pragma unroll
  for (int di = 0; di < 4; ++di) oacc[di] = zero4;

  for (int t = 0; t < 16; ++t) {
    const int kv0 = t * 128;
#pragma unroll
    for (int p = 0; p < 4; ++p) {
      int l = p * 256 + tid;
      int kv = l >> 3, dc = l & 7;
      load_lds16(kbase + (kv0 + kv) * 64 + ((dc ^ (kv & 7)) * 8), Ks + (p * 256 + (tid & 192)) * 8);
    }
#pragma unroll
    for (int p = 0; p < 4; ++p) {
      int l = p * 256 + tid;
      int d = l >> 4, dc = l & 15;
      load_lds16(vbase + (size_t)d * 2048 + kv0 + ((dc ^ (d & 15)) * 8),
                 Vts + (p * 256 + (tid & 192)) * 8);
    }
    __syncthreads();

#pragma unroll
    for (int c = 0; c < 4; ++c) {
      // S^T chunk: 32 kv rows x 16 q cols per wave (A = K frag, B = Q frag)
      f32x4 s0 = zero4, s1 = zero4;
      {
        const int sw0 = (quad ^ (l15 & 7)) * 8;
        bf16x8 ak0 = *(const bf16x8*)(Ks + ((c * 2 + 0) * 16 + l15) * 64 + sw0);
        bf16x8 ak1 = *(const bf16x8*)(Ks + ((c * 2 + 1) * 16 + l15) * 64 + sw0);
        s0 = __builtin_amdgcn_mfma_f32_16x16x32_bf16(ak0, bq0, s0, 0, 0, 0);
        s1 = __builtin_amdgcn_mfma_f32_16x16x32_bf16(ak1, bq0, s1, 0, 0, 0);
        const int sw1 = ((4 + quad) ^ (l15 & 7)) * 8;
        ak0 = *(const bf16x8*)(Ks + ((c * 2 + 0) * 16 + l15) * 64 + sw1);
        ak1 = *(const bf16x8*)(Ks + ((c * 2 + 1) * 16 + l15) * 64 + sw1);
        s0 = __builtin_amdgcn_mfma_f32_16x16x32_bf16(ak0, bq1, s0, 0, 0, 0);
        s1 = __builtin_amdgcn_mfma_f32_16x16x32_bf16(ak1, bq1, s1, 0, 0, 0);
      }

      // p = exp2(s), accumulate l, pack to bf16 pairs (1 VALU op per pair)
      f32x4 pv0, pv1;
#pragma unroll
      for (int r = 0; r < 4; ++r) {
        pv0[r] = __builtin_amdgcn_exp2f(s0[r]);
        pv1[r] = __builtin_amdgcn_exp2f(s1[r]);
      }
      lsumv += pv0;
      lsumv += pv1;
      unsigned int a0 = cvt_pk_bf16(pv0[0], pv0[1]);   // kv = qd*4+0,+1   (s0)
      unsigned int a1 = cvt_pk_bf16(pv0[2], pv0[3]);   // kv = qd*4+2,+3   (s0)
      unsigned int b0 = cvt_pk_bf16(pv1[0], pv1[1]);   // kv = 16+qd*4+0,+1 (s1)
      unsigned int b1 = cvt_pk_bf16(pv1[2], pv1[3]);   // kv = 16+qd*4+2,+3 (s1)

      // cross-quad redistribute: lane (l15,quad) ends with kv = quad*8..+7.
      // swap32: x = {a[q0],a[q1],b[q0],b[q1]}, y = {a[q2],a[q3],b[q2],b[q3]}
      // swap16: p = {x.r0,y.r0,x.r2,y.r2} -> exact A-fragment u32 order.
      u32x2 t0 = __builtin_amdgcn_permlane32_swap(a0, b0, false, false);
      u32x2 t1 = __builtin_amdgcn_permlane32_swap(a1, b1, false, false);
      u32x2 u0 = __builtin_amdgcn_permlane16_swap(t0.x, t0.y, false, false);
      u32x2 u1 = __builtin_amdgcn_permlane16_swap(t1.x, t1.y, false, false);

      union { unsigned int u[4]; bf16x8 v; } P;
      P.u[0] = u0.x;   // kv pairs (8t+0,1)
      P.u[1] = u1.x;   // kv pairs (8t+2,3)
      P.u[2] = u0.y;   // kv pairs (8t+4,5)
      P.u[3] = u1.y;   // kv pairs (8t+6,7)
      bf16x8 ap = P.v;

      // O += P V for this 32-kv chunk (pure in-register A operand)
#pragma unroll
      for (int di = 0; di < 4; ++di) {
        bf16x8 bv = *(const bf16x8*)(Vts + (di * 16 + l15) * 128 + (((c * 4 + quad) ^ l15) * 8));
        oacc[di] = __builtin_amdgcn_mfma_f32_16x16x32_bf16(ap, bv, oacc[di], 0, 0, 0);
      }
    }
    __syncthreads();
  }

  // l reduction: horizontal over r, then across quads (wave-internal).
  // After the xor-reduce, lane l holds the full row-sum for q-row (l&15).
  float lv;
  {
    float v = lsumv[0] + lsumv[1] + lsumv[2] + lsumv[3];
    v += __shfl_xor(v, 16);
    v += __shfl_xor(v, 32);
    lv = v;
  }

  // epilogue: normalize, write [B,S,1024] bf16
  const int b = bh >> 4, h = bh & 15;
#pragma unroll
  for (int r = 0; r < 4; ++r) {
    float linv = 1.0f / __shfl(lv, quad * 4 + r);
    int row = q0 + w * 16 + quad * 4 + r;
    u16* dst = Opk + ((size_t)(b * 2048 + row)) * 1024 + h * 64;
#pragma unroll
    for (int di = 0; di < 4; ++di)
      dst[di * 16 + l15] = f32_to_bf16(oacc[di][r] * linv);
  }
}

// ---------------------------------------------------------------------------

extern "C" void kernel_launch(void* const* d_in, const int* in_sizes, int n_in,
                              void* d_out, int out_size, void* d_ws, size_t ws_size,
                              hipStream_t stream) {
  const float* q   = (const float*)d_in[0];
  const float* c   = (const float*)d_in[1];
  const float* Wkv = (const float*)d_in[2];
  const float* bkv = (const float*)d_in[3];
  const float* Wo  = (const float*)d_in[4];
  const float* bo  = (const float*)d_in[5];
  float* out = (float*)d_out;
  char* ws = (char*)d_ws;

  u16* c_bf = (u16*)(ws + 0);          // 16 MB  [8192,1024] bf16
  u16* qh   = (u16*)(ws + 16777216);   // 16 MB  [64,2048,64]
  u16* Wkvt = (u16*)(ws + 33554432);   //  4 MB  [2048,1024]
  u16* Wot  = (u16*)(ws + 37748736);   //  2 MB  [1024,1024]
  u16* KpB  = (u16*)(ws + 39845888);   // 16 MB  [64,2048,64]
  u16* VtB  = (u16*)(ws + 56623104);   // 16 MB  [64,64,2048]
  u16* Opk  = c_bf;                    // reuse: c_bf dead after gemm<0>

  cvt_cq_kernel<<<8192, 256, 0, stream>>>(c, q, c_bf, qh);
  transpose_w_kernel<<<dim3(32, 16), 256, 0, stream>>>(Wkv, Wkvt, 2048);
  transpose_w_kernel<<<dim3(16, 16), 256, 0, stream>>>(Wo, Wot, 1024);
  gemm128<0><<<dim3(16, 64), 256, 0, stream>>>(c_bf, Wkvt, bkv, KpB, VtB, nullptr, 1024);
  flash_kernel<<<2048, 256, 0, stream>>>(qh, KpB, VtB, Opk);
  gemm128<1><<<dim3(8, 64), 256, 0, stream>>>(Opk, Wot, bo, nullptr, nullptr, out, 1024);
}

// Round 2
// 276.749 us; speedup vs baseline: 1.1027x; 1.0392x over previous
//
#include <hip/hip_runtime.h>

typedef __bf16 bf16x8 __attribute__((ext_vector_type(8)));
typedef float f32x4 __attribute__((ext_vector_type(4)));
typedef unsigned short u16;
typedef unsigned short u16x4 __attribute__((ext_vector_type(4)));
typedef unsigned short u16x8 __attribute__((ext_vector_type(8)));
typedef unsigned int u32x2 __attribute__((ext_vector_type(2)));

#define DEVFN __device__ __forceinline__

DEVFN u16 f32_to_bf16(float f) {
  unsigned int u = __float_as_uint(f);
  u += 0x7FFFu + ((u >> 16) & 1u);   // round-to-nearest-even
  return (u16)(u >> 16);
}

// pack two f32 -> u32 of 2 bf16 (low = a, high = b), single VALU op
DEVFN unsigned int cvt_pk_bf16(float a, float b) {
  unsigned int r;
  asm("v_cvt_pk_bf16_f32 %0, %1, %2" : "=v"(r) : "v"(a), "v"(b));
  return r;
}

DEVFN void load_lds16(const void* g, void* l) {
  __builtin_amdgcn_global_load_lds(
      (__attribute__((address_space(1))) void*)g,
      (__attribute__((address_space(3))) void*)l,
      16, 0, 0);
}

// ---------------------------------------------------------------------------
// prep: c -> bf16 stream; q -> [B,H,S,64] bf16 pre-scaled by 0.125*log2(e)
// ---------------------------------------------------------------------------
__global__ void cvt_cq_kernel(const float* __restrict__ c, const float* __restrict__ q,
                              u16* __restrict__ c_bf, u16* __restrict__ qh) {
  const int bid = blockIdx.x;
  if (bid < 4096) {
    int i = bid * 256 + threadIdx.x;
    const float4* p = (const float4*)c + (size_t)i * 2;
    float4 a = p[0], b = p[1];
    u16x8 o;
    o[0] = f32_to_bf16(a.x); o[1] = f32_to_bf16(a.y);
    o[2] = f32_to_bf16(a.z); o[3] = f32_to_bf16(a.w);
    o[4] = f32_to_bf16(b.x); o[5] = f32_to_bf16(b.y);
    o[6] = f32_to_bf16(b.z); o[7] = f32_to_bf16(b.w);
    *(u16x8*)(c_bf + (size_t)i * 8) = o;
  } else {
    const float SC = 0.125f * 1.44269504088896f;
    int i = (bid - 4096) * 256 + threadIdx.x;
    int dc = i & 7, sx = (i >> 3) & 2047, h = (i >> 14) & 15, b = i >> 18;
    const float4* p = (const float4*)(q + ((size_t)(b * 2048 + sx)) * 1024 + h * 64 + dc * 8);
    float4 a = p[0], bb = p[1];
    u16x8 o;
    o[0] = f32_to_bf16(a.x * SC);  o[1] = f32_to_bf16(a.y * SC);
    o[2] = f32_to_bf16(a.z * SC);  o[3] = f32_to_bf16(a.w * SC);
    o[4] = f32_to_bf16(bb.x * SC); o[5] = f32_to_bf16(bb.y * SC);
    o[6] = f32_to_bf16(bb.z * SC); o[7] = f32_to_bf16(bb.w * SC);
    *(u16x8*)(qh + (size_t)i * 8) = o;
  }
}

// W [1024][N] f32 -> Wt [N][1024] bf16 (64x64 LDS tile transpose)
__global__ void transpose_w_kernel(const float* __restrict__ in, u16* __restrict__ out, int N) {
  __shared__ __align__(16) u16 T[64 * 72];
  const int tid = threadIdx.x;
  const int n0 = blockIdx.x * 64, k0 = blockIdx.y * 64;
#pragma unroll
  for (int p = 0; p < 4; ++p) {
    int l = p * 256 + tid;
    int k = l >> 4, nc = l & 15;
    const float4 v = *(const float4*)(in + (size_t)(k0 + k) * N + n0 + nc * 4);
    T[(nc * 4 + 0) * 72 + k] = f32_to_bf16(v.x);
    T[(nc * 4 + 1) * 72 + k] = f32_to_bf16(v.y);
    T[(nc * 4 + 2) * 72 + k] = f32_to_bf16(v.z);
    T[(nc * 4 + 3) * 72 + k] = f32_to_bf16(v.w);
  }
  __syncthreads();
#pragma unroll
  for (int p = 0; p < 2; ++p) {
    int u = p * 256 + tid;
    int n = u >> 3, kc = u & 7;
    u16x8 o = *(const u16x8*)(T + n * 72 + kc * 8);
    *(u16x8*)(out + (size_t)(n0 + n) * 1024 + k0 + kc * 8) = o;
  }
}

// ---------------------------------------------------------------------------
// 128x128 bf16 GEMM, BK=64, global_load_lds + XOR-swizzled LDS
// MODE 0: KV epilogue — K scattered per head; V transposed via LDS and
//         written directly as Vt [bh][64 d][2048 sx] (kills transpose_v).
// MODE 1: fp32 out (O-proj).
// ---------------------------------------------------------------------------
template <int MODE>
__global__ __launch_bounds__(256, 2) void gemm128(
    const u16* __restrict__ A, const u16* __restrict__ Bt,
    const float* __restrict__ bias,
    u16* __restrict__ outK, u16* __restrict__ outV,
    float* __restrict__ outF, int K) {
  __shared__ __align__(16) u16 SMEM[2 * 128 * 64];   // As | Bs ; reused as VT
  u16* As = SMEM;
  u16* Bs = SMEM + 128 * 64;
  const int tid = threadIdx.x;
  const int lane = tid & 63, w = tid >> 6, quad = lane >> 4, l15 = lane & 15;
  const int wm = w & 1, wn = w >> 1;
  const int tn = blockIdx.x, tm = blockIdx.y;
  const u16* Ab = A + (size_t)tm * 128 * K;
  const u16* Bb = Bt + (size_t)tn * 128 * K;

  const f32x4 zero4 = {0.f, 0.f, 0.f, 0.f};
  f32x4 acc[4][4];
#pragma unroll
  for (int mi = 0; mi < 4; ++mi)
#pragma unroll
    for (int ni = 0; ni < 4; ++ni) acc[mi][ni] = zero4;

  for (int k0 = 0; k0 < K; k0 += 64) {
#pragma unroll
    for (int p = 0; p < 4; ++p) {
      int l = p * 256 + tid;
      int r = l >> 3, dc = l & 7;
      int go = r * K + k0 + ((dc ^ (r & 7)) * 8);
      int lb = (p * 256 + (tid & 192)) * 8;
      load_lds16(Ab + go, As + lb);
      load_lds16(Bb + go, Bs + lb);
    }
    __syncthreads();
#pragma unroll
    for (int kk = 0; kk < 2; ++kk) {
      bf16x8 av[4], bv[4];
#pragma unroll
      for (int i = 0; i < 4; ++i) {
        int sw = ((kk * 4 + quad) ^ (l15 & 7)) * 8;
        av[i] = *(const bf16x8*)(As + (wm * 64 + i * 16 + l15) * 64 + sw);
        bv[i] = *(const bf16x8*)(Bs + (wn * 64 + i * 16 + l15) * 64 + sw);
      }
#pragma unroll
      for (int mi = 0; mi < 4; ++mi)
#pragma unroll
        for (int ni = 0; ni < 4; ++ni)
          acc[mi][ni] = __builtin_amdgcn_mfma_f32_16x16x32_bf16(av[mi], bv[ni], acc[mi][ni], 0, 0, 0);
    }
    __syncthreads();
  }

  if (MODE == 0) {
    // n = tn*128 + wn*64 + ni*16 + l15 ; head h = tn ; rr = wn*64 + ni*16 + l15
    // wn==0 -> K half (rr<64), wn==1 -> V half (rr>=64, d = rr-64)
    const int h = tn;
    const int b = tm >> 4;
    const int sx0 = (tm & 15) * 128;
    u16* VT = SMEM;   // [64 d][128 sx] stride 136 — As/Bs dead after final sync
    if (wn == 0) {
#pragma unroll
      for (int ni = 0; ni < 4; ++ni) {
        const int d = ni * 16 + l15;
        const float bb = bias[tn * 128 + d];
#pragma unroll
        for (int mi = 0; mi < 4; ++mi) {
#pragma unroll
          for (int r = 0; r < 4; ++r) {
            const int sx = sx0 + wm * 64 + mi * 16 + quad * 4 + r;
            outK[((size_t)(b * 16 + h) * 2048 + sx) * 64 + d] = f32_to_bf16(acc[mi][ni][r] + bb);
          }
        }
      }
    } else {
#pragma unroll
      for (int ni = 0; ni < 4; ++ni) {
        const int d = ni * 16 + l15;
        const float bb = bias[tn * 128 + 64 + d];
#pragma unroll
        for (int mi = 0; mi < 4; ++mi) {
          u16x4 pk;
#pragma unroll
          for (int r = 0; r < 4; ++r) pk[r] = f32_to_bf16(acc[mi][ni][r] + bb);
          *(u16x4*)(VT + d * 136 + wm * 64 + mi * 16 + quad * 4) = pk;
        }
      }
    }
    __syncthreads();
    // cooperative coalesced store of VT -> outV [bh][d][sx]
    {
      const int d = tid >> 2, ch = tid & 3;
      u16* dst = outV + (((size_t)(b * 16 + h) * 64 + d) * 2048 + sx0 + ch * 32);
      const u16* src = VT + d * 136 + ch * 32;
#pragma unroll
      for (int i = 0; i < 4; ++i)
        *(u16x8*)(dst + i * 8) = *(const u16x8*)(src + i * 8);
    }
  } else {
#pragma unroll
    for (int ni = 0; ni < 4; ++ni) {
      const int n = tn * 128 + wn * 64 + ni * 16 + l15;
      const float bb = bias[n];
#pragma unroll
      for (int mi = 0; mi < 4; ++mi) {
#pragma unroll
        for (int r = 0; r < 4; ++r) {
          const int m = tm * 128 + wm * 64 + mi * 16 + quad * 4 + r;
          outF[(size_t)m * 1024 + n] = acc[mi][ni][r] + bb;
        }
      }
    }
  }
}

// ---------------------------------------------------------------------------
// flash attention v5: 64-q-row blocks (1 wave = 16 q rows), 2048 blocks.
// S^T = K·Q^T, no online max (logits bounded), P fully in-register via
// exp2 -> v_cvt_pk_bf16_f32 -> permlane32/16_swap (q is lane-local, q=l15).
// NEW: l-sum folded into the matrix pipe — one extra mfma(ap, ones, lacc)
// per chunk gives l[q] in the same C-layout the epilogue consumes
// (row = quad*4+r), killing 8 v_add_f32/chunk + the epilogue shuffle
// reduction. s_setprio(1) fences around the MFMA clusters (T5).
// LDS = Ks+Vts = exactly 32 KB -> 5 blocks/CU.
// ---------------------------------------------------------------------------
__global__ __launch_bounds__(256, 5) void flash_kernel(
    const u16* __restrict__ Qh,   // [BH,2048,64] bf16, pre-scaled
    const u16* __restrict__ Kp,   // [BH,2048,64]
    const u16* __restrict__ Vt,   // [BH,64,2048]
    u16* __restrict__ Opk) {      // [B,2048,1024] bf16
  __shared__ __align__(16) u16 Ks[128 * 64];
  __shared__ __align__(16) u16 Vts[64 * 128];

  const int tid = threadIdx.x;
  const int lane = tid & 63, w = tid >> 6, quad = lane >> 4, l15 = lane & 15;
  // XCD-swizzled mapping: same bh stays on one XCD (L2 K/V reuse)
  const int id = blockIdx.x;
  const int bh = (id & 7) + 8 * (id >> 8);
  const int qt = (id >> 3) & 31;
  const int q0 = qt * 64;

  const u16* kbase = Kp + (size_t)bh * 2048 * 64;
  const u16* vbase = Vt + (size_t)bh * 64 * 2048;

  // Q B-fragments straight from global: B[n=q][k=d], n=l15, k=quad*8+j
  const u16* qrow = Qh + ((size_t)bh * 2048 + q0 + w * 16 + l15) * 64;
  bf16x8 bq0 = *(const bf16x8*)(qrow + quad * 8);
  bf16x8 bq1 = *(const bf16x8*)(qrow + 32 + quad * 8);

  // all-ones bf16 B-fragment for the l-sum MFMA (B[n][k] = 1.0)
  bf16x8 ones;
#pragma unroll
  for (int i = 0; i < 8; ++i) ones[i] = (__bf16)1.0f;

  const f32x4 zero4 = {0.f, 0.f, 0.f, 0.f};
  f32x4 oacc[4];
  f32x4 lacc = zero4;
#pragma unroll
  for (int di = 0; di < 4; ++di) oacc[di] = zero4;

  for (int t = 0; t < 16; ++t) {
    const int kv0 = t * 128;
#pragma unroll
    for (int p = 0; p < 4; ++p) {
      int l = p * 256 + tid;
      int kv = l >> 3, dc = l & 7;
      load_lds16(kbase + (kv0 + kv) * 64 + ((dc ^ (kv & 7)) * 8), Ks + (p * 256 + (tid & 192)) * 8);
    }
#pragma unroll
    for (int p = 0; p < 4; ++p) {
      int l = p * 256 + tid;
      int d = l >> 4, dc = l & 15;
      load_lds16(vbase + (size_t)d * 2048 + kv0 + ((dc ^ (d & 15)) * 8),
                 Vts + (p * 256 + (tid & 192)) * 8);
    }
    __syncthreads();

#pragma unroll
    for (int c = 0; c < 4; ++c) {
      // S^T chunk: 32 kv rows x 16 q cols per wave (A = K frag, B = Q frag)
      f32x4 s0 = zero4, s1 = zero4;
      {
        const int sw0 = (quad ^ (l15 & 7)) * 8;
        bf16x8 ak0 = *(const bf16x8*)(Ks + ((c * 2 + 0) * 16 + l15) * 64 + sw0);
        bf16x8 ak1 = *(const bf16x8*)(Ks + ((c * 2 + 1) * 16 + l15) * 64 + sw0);
        const int sw1 = ((4 + quad) ^ (l15 & 7)) * 8;
        bf16x8 ak2 = *(const bf16x8*)(Ks + ((c * 2 + 0) * 16 + l15) * 64 + sw1);
        bf16x8 ak3 = *(const bf16x8*)(Ks + ((c * 2 + 1) * 16 + l15) * 64 + sw1);
        __builtin_amdgcn_s_setprio(1);
        s0 = __builtin_amdgcn_mfma_f32_16x16x32_bf16(ak0, bq0, s0, 0, 0, 0);
        s1 = __builtin_amdgcn_mfma_f32_16x16x32_bf16(ak1, bq0, s1, 0, 0, 0);
        s0 = __builtin_amdgcn_mfma_f32_16x16x32_bf16(ak2, bq1, s0, 0, 0, 0);
        s1 = __builtin_amdgcn_mfma_f32_16x16x32_bf16(ak3, bq1, s1, 0, 0, 0);
        __builtin_amdgcn_s_setprio(0);
      }

      // p = exp2(s), pack to bf16 pairs (1 VALU op per pair)
      f32x4 pv0, pv1;
#pragma unroll
      for (int r = 0; r < 4; ++r) {
        pv0[r] = __builtin_amdgcn_exp2f(s0[r]);
        pv1[r] = __builtin_amdgcn_exp2f(s1[r]);
      }
      unsigned int a0 = cvt_pk_bf16(pv0[0], pv0[1]);   // kv = qd*4+0,+1   (s0)
      unsigned int a1 = cvt_pk_bf16(pv0[2], pv0[3]);   // kv = qd*4+2,+3   (s0)
      unsigned int b0 = cvt_pk_bf16(pv1[0], pv1[1]);   // kv = 16+qd*4+0,+1 (s1)
      unsigned int b1 = cvt_pk_bf16(pv1[2], pv1[3]);   // kv = 16+qd*4+2,+3 (s1)

      // cross-quad redistribute: lane (l15,quad) ends with kv = quad*8..+7.
      // swap32: x = {a[q0],a[q1],b[q0],b[q1]}, y = {a[q2],a[q3],b[q2],b[q3]}
      // swap16: p = {x.r0,y.r0,x.r2,y.r2} -> exact A-fragment u32 order.
      u32x2 t0 = __builtin_amdgcn_permlane32_swap(a0, b0, false, false);
      u32x2 t1 = __builtin_amdgcn_permlane32_swap(a1, b1, false, false);
      u32x2 u0 = __builtin_amdgcn_permlane16_swap(t0.x, t0.y, false, false);
      u32x2 u1 = __builtin_amdgcn_permlane16_swap(t1.x, t1.y, false, false);

      union { unsigned int u[4]; bf16x8 v; } P;
      P.u[0] = u0.x;   // kv pairs (8t+0,1)
      P.u[1] = u1.x;   // kv pairs (8t+2,3)
      P.u[2] = u0.y;   // kv pairs (8t+4,5)
      P.u[3] = u1.y;   // kv pairs (8t+6,7)
      bf16x8 ap = P.v;

      // O += P V for this 32-kv chunk; l += P·1 on the same pipe
      bf16x8 bv0 = *(const bf16x8*)(Vts + (0 * 16 + l15) * 128 + (((c * 4 + quad) ^ l15) * 8));
      bf16x8 bv1 = *(const bf16x8*)(Vts + (1 * 16 + l15) * 128 + (((c * 4 + quad) ^ l15) * 8));
      bf16x8 bv2 = *(const bf16x8*)(Vts + (2 * 16 + l15) * 128 + (((c * 4 + quad) ^ l15) * 8));
      bf16x8 bv3 = *(const bf16x8*)(Vts + (3 * 16 + l15) * 128 + (((c * 4 + quad) ^ l15) * 8));
      __builtin_amdgcn_s_setprio(1);
      oacc[0] = __builtin_amdgcn_mfma_f32_16x16x32_bf16(ap, bv0, oacc[0], 0, 0, 0);
      oacc[1] = __builtin_amdgcn_mfma_f32_16x16x32_bf16(ap, bv1, oacc[1], 0, 0, 0);
      oacc[2] = __builtin_amdgcn_mfma_f32_16x16x32_bf16(ap, bv2, oacc[2], 0, 0, 0);
      oacc[3] = __builtin_amdgcn_mfma_f32_16x16x32_bf16(ap, bv3, oacc[3], 0, 0, 0);
      lacc = __builtin_amdgcn_mfma_f32_16x16x32_bf16(ap, ones, lacc, 0, 0, 0);
      __builtin_amdgcn_s_setprio(0);
    }
    __syncthreads();
  }

  // epilogue: normalize, write [B,S,1024] bf16.
  // lacc C-layout: row = quad*4+r = q (mod 16), col = l15 (all cols equal)
  // -> linv for row quad*4+r is simply 1/lacc[r]; no cross-lane reduction.
  const int b = bh >> 4, h = bh & 15;
#pragma unroll
  for (int r = 0; r < 4; ++r) {
    float linv = 1.0f / lacc[r];
    int row = q0 + w * 16 + quad * 4 + r;
    u16* dst = Opk + ((size_t)(b * 2048 + row)) * 1024 + h * 64;
#pragma unroll
    for (int di = 0; di < 4; ++di)
      dst[di * 16 + l15] = f32_to_bf16(oacc[di][r] * linv);
  }
}

// ---------------------------------------------------------------------------

extern "C" void kernel_launch(void* const* d_in, const int* in_sizes, int n_in,
                              void* d_out, int out_size, void* d_ws, size_t ws_size,
                              hipStream_t stream) {
  const float* q   = (const float*)d_in[0];
  const float* c   = (const float*)d_in[1];
  const float* Wkv = (const float*)d_in[2];
  const float* bkv = (const float*)d_in[3];
  const float* Wo  = (const float*)d_in[4];
  const float* bo  = (const float*)d_in[5];
  float* out = (float*)d_out;
  char* ws = (char*)d_ws;

  u16* c_bf = (u16*)(ws + 0);          // 16 MB  [8192,1024] bf16
  u16* qh   = (u16*)(ws + 16777216);   // 16 MB  [64,2048,64]
  u16* Wkvt = (u16*)(ws + 33554432);   //  4 MB  [2048,1024]
  u16* Wot  = (u16*)(ws + 37748736);   //  2 MB  [1024,1024]
  u16* KpB  = (u16*)(ws + 39845888);   // 16 MB  [64,2048,64]
  u16* VtB  = (u16*)(ws + 56623104);   // 16 MB  [64,64,2048]
  u16* Opk  = c_bf;                    // reuse: c_bf dead after gemm<0>

  cvt_cq_kernel<<<8192, 256, 0, stream>>>(c, q, c_bf, qh);
  transpose_w_kernel<<<dim3(32, 16), 256, 0, stream>>>(Wkv, Wkvt, 2048);
  transpose_w_kernel<<<dim3(16, 16), 256, 0, stream>>>(Wo, Wot, 1024);
  gemm128<0><<<dim3(16, 64), 256, 0, stream>>>(c_bf, Wkvt, bkv, KpB, VtB, nullptr, 1024);
  flash_kernel<<<2048, 256, 0, stream>>>(qh, KpB, VtB, Opk);
  gemm128<1><<<dim3(8, 64), 256, 0, stream>>>(Opk, Wot, bo, nullptr, nullptr, out, 1024);
}

// Round 5
// 274.885 us; speedup vs baseline: 1.1102x; 1.0068x over previous
//
#include <hip/hip_runtime.h>

typedef __bf16 bf16x8 __attribute__((ext_vector_type(8)));
typedef float f32x4 __attribute__((ext_vector_type(4)));
typedef unsigned short u16;
typedef unsigned short u16x4 __attribute__((ext_vector_type(4)));
typedef unsigned short u16x8 __attribute__((ext_vector_type(8)));
typedef unsigned int u32x2 __attribute__((ext_vector_type(2)));

#define DEVFN __device__ __forceinline__

DEVFN u16 f32_to_bf16(float f) {
  unsigned int u = __float_as_uint(f);
  u += 0x7FFFu + ((u >> 16) & 1u);   // round-to-nearest-even
  return (u16)(u >> 16);
}

// pack two f32 -> u32 of 2 bf16 (low = a, high = b), single VALU op
DEVFN unsigned int cvt_pk_bf16(float a, float b) {
  unsigned int r;
  asm("v_cvt_pk_bf16_f32 %0, %1, %2" : "=v"(r) : "v"(a), "v"(b));
  return r;
}

DEVFN void load_lds16(const void* g, void* l) {
  __builtin_amdgcn_global_load_lds(
      (__attribute__((address_space(1))) void*)g,
      (__attribute__((address_space(3))) void*)l,
      16, 0, 0);
}

// ---------------------------------------------------------------------------
// prep: c -> bf16 stream; q -> [B,H,S,64] bf16 pre-scaled by 0.125*log2(e)
// ---------------------------------------------------------------------------
__global__ void cvt_cq_kernel(const float* __restrict__ c, const float* __restrict__ q,
                              u16* __restrict__ c_bf, u16* __restrict__ qh) {
  const int bid = blockIdx.x;
  if (bid < 4096) {
    int i = bid * 256 + threadIdx.x;
    const float4* p = (const float4*)c + (size_t)i * 2;
    float4 a = p[0], b = p[1];
    u16x8 o;
    o[0] = f32_to_bf16(a.x); o[1] = f32_to_bf16(a.y);
    o[2] = f32_to_bf16(a.z); o[3] = f32_to_bf16(a.w);
    o[4] = f32_to_bf16(b.x); o[5] = f32_to_bf16(b.y);
    o[6] = f32_to_bf16(b.z); o[7] = f32_to_bf16(b.w);
    *(u16x8*)(c_bf + (size_t)i * 8) = o;
  } else {
    const float SC = 0.125f * 1.44269504088896f;
    int i = (bid - 4096) * 256 + threadIdx.x;
    int dc = i & 7, sx = (i >> 3) & 2047, h = (i >> 14) & 15, b = i >> 18;
    const float4* p = (const float4*)(q + ((size_t)(b * 2048 + sx)) * 1024 + h * 64 + dc * 8);
    float4 a = p[0], bb = p[1];
    u16x8 o;
    o[0] = f32_to_bf16(a.x * SC);  o[1] = f32_to_bf16(a.y * SC);
    o[2] = f32_to_bf16(a.z * SC);  o[3] = f32_to_bf16(a.w * SC);
    o[4] = f32_to_bf16(bb.x * SC); o[5] = f32_to_bf16(bb.y * SC);
    o[6] = f32_to_bf16(bb.z * SC); o[7] = f32_to_bf16(bb.w * SC);
    *(u16x8*)(qh + (size_t)i * 8) = o;
  }
}

// W [1024][N] f32 -> Wt [N][1024] bf16 (64x64 LDS tile transpose)
__global__ void transpose_w_kernel(const float* __restrict__ in, u16* __restrict__ out, int N) {
  __shared__ __align__(16) u16 T[64 * 72];
  const int tid = threadIdx.x;
  const int n0 = blockIdx.x * 64, k0 = blockIdx.y * 64;
#pragma unroll
  for (int p = 0; p < 4; ++p) {
    int l = p * 256 + tid;
    int k = l >> 4, nc = l & 15;
    const float4 v = *(const float4*)(in + (size_t)(k0 + k) * N + n0 + nc * 4);
    T[(nc * 4 + 0) * 72 + k] = f32_to_bf16(v.x);
    T[(nc * 4 + 1) * 72 + k] = f32_to_bf16(v.y);
    T[(nc * 4 + 2) * 72 + k] = f32_to_bf16(v.z);
    T[(nc * 4 + 3) * 72 + k] = f32_to_bf16(v.w);
  }
  __syncthreads();
#pragma unroll
  for (int p = 0; p < 2; ++p) {
    int u = p * 256 + tid;
    int n = u >> 3, kc = u & 7;
    u16x8 o = *(const u16x8*)(T + n * 72 + kc * 8);
    *(u16x8*)(out + (size_t)(n0 + n) * 1024 + k0 + kc * 8) = o;
  }
}

// ---------------------------------------------------------------------------
// 128x128 bf16 GEMM, BK=64, global_load_lds + XOR-swizzled LDS
// MODE 0: KV epilogue — K scattered per head; V transposed via LDS and
//         written directly as Vt [bh][64 d][2048 sx] (kills transpose_v).
// MODE 1: fp32 out (O-proj).
// ---------------------------------------------------------------------------
template <int MODE>
__global__ __launch_bounds__(256, 2) void gemm128(
    const u16* __restrict__ A, const u16* __restrict__ Bt,
    const float* __restrict__ bias,
    u16* __restrict__ outK, u16* __restrict__ outV,
    float* __restrict__ outF, int K) {
  __shared__ __align__(16) u16 SMEM[2 * 128 * 64];   // As | Bs ; reused as VT
  u16* As = SMEM;
  u16* Bs = SMEM + 128 * 64;
  const int tid = threadIdx.x;
  const int lane = tid & 63, w = tid >> 6, quad = lane >> 4, l15 = lane & 15;
  const int wm = w & 1, wn = w >> 1;
  const int tn = blockIdx.x, tm = blockIdx.y;
  const u16* Ab = A + (size_t)tm * 128 * K;
  const u16* Bb = Bt + (size_t)tn * 128 * K;

  const f32x4 zero4 = {0.f, 0.f, 0.f, 0.f};
  f32x4 acc[4][4];
#pragma unroll
  for (int mi = 0; mi < 4; ++mi)
#pragma unroll
    for (int ni = 0; ni < 4; ++ni) acc[mi][ni] = zero4;

  for (int k0 = 0; k0 < K; k0 += 64) {
#pragma unroll
    for (int p = 0; p < 4; ++p) {
      int l = p * 256 + tid;
      int r = l >> 3, dc = l & 7;
      int go = r * K + k0 + ((dc ^ (r & 7)) * 8);
      int lb = (p * 256 + (tid & 192)) * 8;
      load_lds16(Ab + go, As + lb);
      load_lds16(Bb + go, Bs + lb);
    }
    __syncthreads();
#pragma unroll
    for (int kk = 0; kk < 2; ++kk) {
      bf16x8 av[4], bv[4];
#pragma unroll
      for (int i = 0; i < 4; ++i) {
        int sw = ((kk * 4 + quad) ^ (l15 & 7)) * 8;
        av[i] = *(const bf16x8*)(As + (wm * 64 + i * 16 + l15) * 64 + sw);
        bv[i] = *(const bf16x8*)(Bs + (wn * 64 + i * 16 + l15) * 64 + sw);
      }
#pragma unroll
      for (int mi = 0; mi < 4; ++mi)
#pragma unroll
        for (int ni = 0; ni < 4; ++ni)
          acc[mi][ni] = __builtin_amdgcn_mfma_f32_16x16x32_bf16(av[mi], bv[ni], acc[mi][ni], 0, 0, 0);
    }
    __syncthreads();
  }

  if (MODE == 0) {
    // n = tn*128 + wn*64 + ni*16 + l15 ; head h = tn ; rr = wn*64 + ni*16 + l15
    // wn==0 -> K half (rr<64), wn==1 -> V half (rr>=64, d = rr-64)
    const int h = tn;
    const int b = tm >> 4;
    const int sx0 = (tm & 15) * 128;
    u16* VT = SMEM;   // [64 d][128 sx] stride 136 — As/Bs dead after final sync
    if (wn == 0) {
#pragma unroll
      for (int ni = 0; ni < 4; ++ni) {
        const int d = ni * 16 + l15;
        const float bb = bias[tn * 128 + d];
#pragma unroll
        for (int mi = 0; mi < 4; ++mi) {
#pragma unroll
          for (int r = 0; r < 4; ++r) {
            const int sx = sx0 + wm * 64 + mi * 16 + quad * 4 + r;
            outK[((size_t)(b * 16 + h) * 2048 + sx) * 64 + d] = f32_to_bf16(acc[mi][ni][r] + bb);
          }
        }
      }
    } else {
#pragma unroll
      for (int ni = 0; ni < 4; ++ni) {
        const int d = ni * 16 + l15;
        const float bb = bias[tn * 128 + 64 + d];
#pragma unroll
        for (int mi = 0; mi < 4; ++mi) {
          u16x4 pk;
#pragma unroll
          for (int r = 0; r < 4; ++r) pk[r] = f32_to_bf16(acc[mi][ni][r] + bb);
          *(u16x4*)(VT + d * 136 + wm * 64 + mi * 16 + quad * 4) = pk;
        }
      }
    }
    __syncthreads();
    // cooperative coalesced store of VT -> outV [bh][d][sx]
    {
      const int d = tid >> 2, ch = tid & 3;
      u16* dst = outV + (((size_t)(b * 16 + h) * 64 + d) * 2048 + sx0 + ch * 32);
      const u16* src = VT + d * 136 + ch * 32;
#pragma unroll
      for (int i = 0; i < 4; ++i)
        *(u16x8*)(dst + i * 8) = *(const u16x8*)(src + i * 8);
    }
  } else {
#pragma unroll
    for (int ni = 0; ni < 4; ++ni) {
      const int n = tn * 128 + wn * 64 + ni * 16 + l15;
      const float bb = bias[n];
#pragma unroll
      for (int mi = 0; mi < 4; ++mi) {
#pragma unroll
        for (int r = 0; r < 4; ++r) {
          const int m = tm * 128 + wm * 64 + mi * 16 + quad * 4 + r;
          outF[(size_t)m * 1024 + n] = acc[mi][ni][r] + bb;
        }
      }
    }
  }
}

// ---------------------------------------------------------------------------
// flash attention v7: 64-q-row blocks (1 wave = 16 q rows), 2048 blocks.
// S^T = K·Q^T, P fully in-register (cvt_pk + permlane), l via mfma(ap,1).
// T3+T4: KVBLK=64 double-buffered pipeline with counted vmcnt.
// FIX vs v6: no tail re-stage. Last iteration stages nothing and drains
// vmcnt(0), so ZERO global_load_lds are outstanding at s_endpgm (v6 exited
// with 4 in-flight DMA writes into LDS -> possible corruption/fault after
// workgroup retirement -> suspected container kill in R3/R4).
// The t<31 branch is wave-uniform, so barriers stay uniform.
// vmcnt FIFO per iter t<31: 4 outstanding (tile t) + stage 4 (tile t+1)
// -> vmcnt(4) retires exactly tile t's loads. t=31: vmcnt(0) drains.
// LDS = 2*(8KB K + 8KB V) = exactly 32 KB -> 5 blocks/CU.
// ---------------------------------------------------------------------------
__global__ __launch_bounds__(256, 5) void flash_kernel(
    const u16* __restrict__ Qh,   // [BH,2048,64] bf16, pre-scaled
    const u16* __restrict__ Kp,   // [BH,2048,64]
    const u16* __restrict__ Vt,   // [BH,64,2048]
    u16* __restrict__ Opk) {      // [B,2048,1024] bf16
  __shared__ __align__(16) u16 Ks[2][64 * 64];
  __shared__ __align__(16) u16 Vts[2][64 * 64];

  const int tid = threadIdx.x;
  const int lane = tid & 63, w = tid >> 6, quad = lane >> 4, l15 = lane & 15;
  // XCD-swizzled mapping: same bh stays on one XCD (L2 K/V reuse)
  const int id = blockIdx.x;
  const int bh = (id & 7) + 8 * (id >> 8);
  const int qt = (id >> 3) & 31;
  const int q0 = qt * 64;

  const u16* kbase = Kp + (size_t)bh * 2048 * 64;
  const u16* vbase = Vt + (size_t)bh * 64 * 2048;

  // Q B-fragments straight from global: B[n=q][k=d], n=l15, k=quad*8+j
  const u16* qrow = Qh + ((size_t)bh * 2048 + q0 + w * 16 + l15) * 64;
  bf16x8 bq0 = *(const bf16x8*)(qrow + quad * 8);
  bf16x8 bq1 = *(const bf16x8*)(qrow + 32 + quad * 8);

  // all-ones bf16 B-fragment for the l-sum MFMA (B[n][k] = 1.0)
  bf16x8 ones;
#pragma unroll
  for (int i = 0; i < 8; ++i) ones[i] = (__bf16)1.0f;

  const f32x4 zero4 = {0.f, 0.f, 0.f, 0.f};
  f32x4 oacc[4];
  f32x4 lacc = zero4;
#pragma unroll
  for (int di = 0; di < 4; ++di) oacc[di] = zero4;

  // thread-constant staging coordinates
  const int skv = tid >> 3, sdc = tid & 7;          // K: row skv(+32), chunk sdc
  const int ksw = (sdc ^ (skv & 7)) * 8;            // XOR swizzle (row&7); (skv+32)&7 == skv&7
  const int ldst = ((tid & 192) * 8);               // wave-uniform LDS page base

  // stage tile tt into buffer bi (4 global_load_lds, 16B each)
#define STAGE(tt, bi)                                                              \
  do {                                                                             \
    const int kv0_ = (tt)*64;                                                      \
    load_lds16(kbase + (size_t)(kv0_ + skv) * 64 + ksw, &Ks[bi][ldst]);            \
    load_lds16(kbase + (size_t)(kv0_ + skv + 32) * 64 + ksw, &Ks[bi][2048 + ldst]); \
    load_lds16(vbase + (size_t)skv * 2048 + kv0_ + ksw, &Vts[bi][ldst]);           \
    load_lds16(vbase + (size_t)(skv + 32) * 2048 + kv0_ + ksw, &Vts[bi][2048 + ldst]); \
  } while (0)

  STAGE(0, 0);

  const int sw0 = (quad ^ (l15 & 7)) * 8;
  const int sw1 = ((4 + quad) ^ (l15 & 7)) * 8;

  for (int t = 0; t < 32; ++t) {
    const int cur = t & 1;
    if (t < 31) {                       // wave-uniform branch
      STAGE(t + 1, cur ^ 1);
      asm volatile("s_waitcnt vmcnt(4)" ::: "memory");
    } else {
      asm volatile("s_waitcnt vmcnt(0)" ::: "memory");
    }
    __builtin_amdgcn_s_barrier();
    asm volatile("" ::: "memory");

    const u16* Ksb = &Ks[cur][0];
    const u16* Vtsb = &Vts[cur][0];
#pragma unroll
    for (int c2 = 0; c2 < 2; ++c2) {
      // S^T chunk: 32 kv rows x 16 q cols per wave (A = K frag, B = Q frag)
      f32x4 s0 = zero4, s1 = zero4;
      {
        bf16x8 ak0 = *(const bf16x8*)(Ksb + ((c2 * 2 + 0) * 16 + l15) * 64 + sw0);
        bf16x8 ak1 = *(const bf16x8*)(Ksb + ((c2 * 2 + 1) * 16 + l15) * 64 + sw0);
        bf16x8 ak2 = *(const bf16x8*)(Ksb + ((c2 * 2 + 0) * 16 + l15) * 64 + sw1);
        bf16x8 ak3 = *(const bf16x8*)(Ksb + ((c2 * 2 + 1) * 16 + l15) * 64 + sw1);
        __builtin_amdgcn_s_setprio(1);
        s0 = __builtin_amdgcn_mfma_f32_16x16x32_bf16(ak0, bq0, s0, 0, 0, 0);
        s1 = __builtin_amdgcn_mfma_f32_16x16x32_bf16(ak1, bq0, s1, 0, 0, 0);
        s0 = __builtin_amdgcn_mfma_f32_16x16x32_bf16(ak2, bq1, s0, 0, 0, 0);
        s1 = __builtin_amdgcn_mfma_f32_16x16x32_bf16(ak3, bq1, s1, 0, 0, 0);
        __builtin_amdgcn_s_setprio(0);
      }

      // p = exp2(s), pack to bf16 pairs (1 VALU op per pair)
      f32x4 pv0, pv1;
#pragma unroll
      for (int r = 0; r < 4; ++r) {
        pv0[r] = __builtin_amdgcn_exp2f(s0[r]);
        pv1[r] = __builtin_amdgcn_exp2f(s1[r]);
      }
      unsigned int a0 = cvt_pk_bf16(pv0[0], pv0[1]);   // kv = qd*4+0,+1   (s0)
      unsigned int a1 = cvt_pk_bf16(pv0[2], pv0[3]);   // kv = qd*4+2,+3   (s0)
      unsigned int b0 = cvt_pk_bf16(pv1[0], pv1[1]);   // kv = 16+qd*4+0,+1 (s1)
      unsigned int b1 = cvt_pk_bf16(pv1[2], pv1[3]);   // kv = 16+qd*4+2,+3 (s1)

      // cross-quad redistribute: lane (l15,quad) ends with kv = quad*8..+7.
      u32x2 t0 = __builtin_amdgcn_permlane32_swap(a0, b0, false, false);
      u32x2 t1 = __builtin_amdgcn_permlane32_swap(a1, b1, false, false);
      u32x2 u0 = __builtin_amdgcn_permlane16_swap(t0.x, t0.y, false, false);
      u32x2 u1 = __builtin_amdgcn_permlane16_swap(t1.x, t1.y, false, false);

      union { unsigned int u[4]; bf16x8 v; } P;
      P.u[0] = u0.x;   // kv pairs (8t+0,1)
      P.u[1] = u1.x;   // kv pairs (8t+2,3)
      P.u[2] = u0.y;   // kv pairs (8t+4,5)
      P.u[3] = u1.y;   // kv pairs (8t+6,7)
      bf16x8 ap = P.v;

      // O += P V for this 32-kv chunk; l += P·1 on the same pipe
      bf16x8 bv0 = *(const bf16x8*)(Vtsb + (0 * 16 + l15) * 64 + (((c2 * 4 + quad) ^ (l15 & 7)) * 8));
      bf16x8 bv1 = *(const bf16x8*)(Vtsb + (1 * 16 + l15) * 64 + (((c2 * 4 + quad) ^ (l15 & 7)) * 8));
      bf16x8 bv2 = *(const bf16x8*)(Vtsb + (2 * 16 + l15) * 64 + (((c2 * 4 + quad) ^ (l15 & 7)) * 8));
      bf16x8 bv3 = *(const bf16x8*)(Vtsb + (3 * 16 + l15) * 64 + (((c2 * 4 + quad) ^ (l15 & 7)) * 8));
      __builtin_amdgcn_s_setprio(1);
      oacc[0] = __builtin_amdgcn_mfma_f32_16x16x32_bf16(ap, bv0, oacc[0], 0, 0, 0);
      oacc[1] = __builtin_amdgcn_mfma_f32_16x16x32_bf16(ap, bv1, oacc[1], 0, 0, 0);
      oacc[2] = __builtin_amdgcn_mfma_f32_16x16x32_bf16(ap, bv2, oacc[2], 0, 0, 0);
      oacc[3] = __builtin_amdgcn_mfma_f32_16x16x32_bf16(ap, bv3, oacc[3], 0, 0, 0);
      lacc = __builtin_amdgcn_mfma_f32_16x16x32_bf16(ap, ones, lacc, 0, 0, 0);
      __builtin_amdgcn_s_setprio(0);
    }
    asm volatile("" ::: "memory");
    __builtin_amdgcn_s_barrier();
    asm volatile("" ::: "memory");
  }
#undef STAGE

  // epilogue: normalize, write [B,S,1024] bf16.
  // lacc C-layout: row = quad*4+r = q (mod 16), col = l15 (all cols equal)
  // -> linv for row quad*4+r is simply 1/lacc[r]; no cross-lane reduction.
  const int b = bh >> 4, h = bh & 15;
#pragma unroll
  for (int r = 0; r < 4; ++r) {
    float linv = 1.0f / lacc[r];
    int row = q0 + w * 16 + quad * 4 + r;
    u16* dst = Opk + ((size_t)(b * 2048 + row)) * 1024 + h * 64;
#pragma unroll
    for (int di = 0; di < 4; ++di)
      dst[di * 16 + l15] = f32_to_bf16(oacc[di][r] * linv);
  }
}

// ---------------------------------------------------------------------------

extern "C" void kernel_launch(void* const* d_in, const int* in_sizes, int n_in,
                              void* d_out, int out_size, void* d_ws, size_t ws_size,
                              hipStream_t stream) {
  const float* q   = (const float*)d_in[0];
  const float* c   = (const float*)d_in[1];
  const float* Wkv = (const float*)d_in[2];
  const float* bkv = (const float*)d_in[3];
  const float* Wo  = (const float*)d_in[4];
  const float* bo  = (const float*)d_in[5];
  float* out = (float*)d_out;
  char* ws = (char*)d_ws;

  u16* c_bf = (u16*)(ws + 0);          // 16 MB  [8192,1024] bf16
  u16* qh   = (u16*)(ws + 16777216);   // 16 MB  [64,2048,64]
  u16* Wkvt = (u16*)(ws + 33554432);   //  4 MB  [2048,1024]
  u16* Wot  = (u16*)(ws + 37748736);   //  2 MB  [1024,1024]
  u16* KpB  = (u16*)(ws + 39845888);   // 16 MB  [64,2048,64]
  u16* VtB  = (u16*)(ws + 56623104);   // 16 MB  [64,64,2048]
  u16* Opk  = c_bf;                    // reuse: c_bf dead after gemm<0>

  cvt_cq_kernel<<<8192, 256, 0, stream>>>(c, q, c_bf, qh);
  transpose_w_kernel<<<dim3(32, 16), 256, 0, stream>>>(Wkv, Wkvt, 2048);
  transpose_w_kernel<<<dim3(16, 16), 256, 0, stream>>>(Wo, Wot, 1024);
  gemm128<0><<<dim3(16, 64), 256, 0, stream>>>(c_bf, Wkvt, bkv, KpB, VtB, nullptr, 1024);
  flash_kernel<<<2048, 256, 0, stream>>>(qh, KpB, VtB, Opk);
  gemm128<1><<<dim3(8, 64), 256, 0, stream>>>(Opk, Wot, bo, nullptr, nullptr, out, 1024);
}

// Round 6
// 258.940 us; speedup vs baseline: 1.1786x; 1.0616x over previous
//
#include <hip/hip_runtime.h>

typedef __bf16 bf16x8 __attribute__((ext_vector_type(8)));
typedef float f32x4 __attribute__((ext_vector_type(4)));
typedef unsigned short u16;
typedef unsigned short u16x4 __attribute__((ext_vector_type(4)));
typedef unsigned short u16x8 __attribute__((ext_vector_type(8)));
typedef unsigned int u32x2 __attribute__((ext_vector_type(2)));

#define DEVFN __device__ __forceinline__

DEVFN u16 f32_to_bf16(float f) {
  unsigned int u = __float_as_uint(f);
  u += 0x7FFFu + ((u >> 16) & 1u);   // round-to-nearest-even
  return (u16)(u >> 16);
}

// pack two f32 -> u32 of 2 bf16 (low = a, high = b), single VALU op
DEVFN unsigned int cvt_pk_bf16(float a, float b) {
  unsigned int r;
  asm("v_cvt_pk_bf16_f32 %0, %1, %2" : "=v"(r) : "v"(a), "v"(b));
  return r;
}

DEVFN void load_lds16(const void* g, void* l) {
  __builtin_amdgcn_global_load_lds(
      (__attribute__((address_space(1))) void*)g,
      (__attribute__((address_space(3))) void*)l,
      16, 0, 0);
}

// ---------------------------------------------------------------------------
// prep: c -> bf16 stream (q is consumed directly by flash_kernel as f32)
// ---------------------------------------------------------------------------
__global__ void cvt_cq_kernel(const float* __restrict__ c, u16* __restrict__ c_bf) {
  int i = blockIdx.x * 256 + threadIdx.x;
  const float4* p = (const float4*)c + (size_t)i * 2;
  float4 a = p[0], b = p[1];
  u16x8 o;
  o[0] = f32_to_bf16(a.x); o[1] = f32_to_bf16(a.y);
  o[2] = f32_to_bf16(a.z); o[3] = f32_to_bf16(a.w);
  o[4] = f32_to_bf16(b.x); o[5] = f32_to_bf16(b.y);
  o[6] = f32_to_bf16(b.z); o[7] = f32_to_bf16(b.w);
  *(u16x8*)(c_bf + (size_t)i * 8) = o;
}

// W [1024][N] f32 -> Wt [N][1024] bf16 (64x64 LDS tile transpose)
__global__ void transpose_w_kernel(const float* __restrict__ in, u16* __restrict__ out, int N) {
  __shared__ __align__(16) u16 T[64 * 72];
  const int tid = threadIdx.x;
  const int n0 = blockIdx.x * 64, k0 = blockIdx.y * 64;
#pragma unroll
  for (int p = 0; p < 4; ++p) {
    int l = p * 256 + tid;
    int k = l >> 4, nc = l & 15;
    const float4 v = *(const float4*)(in + (size_t)(k0 + k) * N + n0 + nc * 4);
    T[(nc * 4 + 0) * 72 + k] = f32_to_bf16(v.x);
    T[(nc * 4 + 1) * 72 + k] = f32_to_bf16(v.y);
    T[(nc * 4 + 2) * 72 + k] = f32_to_bf16(v.z);
    T[(nc * 4 + 3) * 72 + k] = f32_to_bf16(v.w);
  }
  __syncthreads();
#pragma unroll
  for (int p = 0; p < 2; ++p) {
    int u = p * 256 + tid;
    int n = u >> 3, kc = u & 7;
    u16x8 o = *(const u16x8*)(T + n * 72 + kc * 8);
    *(u16x8*)(out + (size_t)(n0 + n) * 1024 + k0 + kc * 8) = o;
  }
}

// ---------------------------------------------------------------------------
// 128x128 bf16 GEMM, BK=64, global_load_lds + XOR-swizzled LDS
// MODE 0: KV epilogue — K scattered per head; V transposed via LDS and
//         written directly as Vt [bh][64 d][2048 sx] (kills transpose_v).
// MODE 1: fp32 out (O-proj).
// ---------------------------------------------------------------------------
template <int MODE>
__global__ __launch_bounds__(256, 2) void gemm128(
    const u16* __restrict__ A, const u16* __restrict__ Bt,
    const float* __restrict__ bias,
    u16* __restrict__ outK, u16* __restrict__ outV,
    float* __restrict__ outF, int K) {
  __shared__ __align__(16) u16 SMEM[2 * 128 * 64];   // As | Bs ; reused as VT
  u16* As = SMEM;
  u16* Bs = SMEM + 128 * 64;
  const int tid = threadIdx.x;
  const int lane = tid & 63, w = tid >> 6, quad = lane >> 4, l15 = lane & 15;
  const int wm = w & 1, wn = w >> 1;
  const int tn = blockIdx.x, tm = blockIdx.y;
  const u16* Ab = A + (size_t)tm * 128 * K;
  const u16* Bb = Bt + (size_t)tn * 128 * K;

  const f32x4 zero4 = {0.f, 0.f, 0.f, 0.f};
  f32x4 acc[4][4];
#pragma unroll
  for (int mi = 0; mi < 4; ++mi)
#pragma unroll
    for (int ni = 0; ni < 4; ++ni) acc[mi][ni] = zero4;

  for (int k0 = 0; k0 < K; k0 += 64) {
#pragma unroll
    for (int p = 0; p < 4; ++p) {
      int l = p * 256 + tid;
      int r = l >> 3, dc = l & 7;
      int go = r * K + k0 + ((dc ^ (r & 7)) * 8);
      int lb = (p * 256 + (tid & 192)) * 8;
      load_lds16(Ab + go, As + lb);
      load_lds16(Bb + go, Bs + lb);
    }
    __syncthreads();
#pragma unroll
    for (int kk = 0; kk < 2; ++kk) {
      bf16x8 av[4], bv[4];
#pragma unroll
      for (int i = 0; i < 4; ++i) {
        int sw = ((kk * 4 + quad) ^ (l15 & 7)) * 8;
        av[i] = *(const bf16x8*)(As + (wm * 64 + i * 16 + l15) * 64 + sw);
        bv[i] = *(const bf16x8*)(Bs + (wn * 64 + i * 16 + l15) * 64 + sw);
      }
#pragma unroll
      for (int mi = 0; mi < 4; ++mi)
#pragma unroll
        for (int ni = 0; ni < 4; ++ni)
          acc[mi][ni] = __builtin_amdgcn_mfma_f32_16x16x32_bf16(av[mi], bv[ni], acc[mi][ni], 0, 0, 0);
    }
    __syncthreads();
  }

  if (MODE == 0) {
    // n = tn*128 + wn*64 + ni*16 + l15 ; head h = tn ; rr = wn*64 + ni*16 + l15
    // wn==0 -> K half (rr<64), wn==1 -> V half (rr>=64, d = rr-64)
    const int h = tn;
    const int b = tm >> 4;
    const int sx0 = (tm & 15) * 128;
    u16* VT = SMEM;   // [64 d][128 sx] stride 136 — As/Bs dead after final sync
    if (wn == 0) {
#pragma unroll
      for (int ni = 0; ni < 4; ++ni) {
        const int d = ni * 16 + l15;
        const float bb = bias[tn * 128 + d];
#pragma unroll
        for (int mi = 0; mi < 4; ++mi) {
#pragma unroll
          for (int r = 0; r < 4; ++r) {
            const int sx = sx0 + wm * 64 + mi * 16 + quad * 4 + r;
            outK[((size_t)(b * 16 + h) * 2048 + sx) * 64 + d] = f32_to_bf16(acc[mi][ni][r] + bb);
          }
        }
      }
    } else {
#pragma unroll
      for (int ni = 0; ni < 4; ++ni) {
        const int d = ni * 16 + l15;
        const float bb = bias[tn * 128 + 64 + d];
#pragma unroll
        for (int mi = 0; mi < 4; ++mi) {
          u16x4 pk;
#pragma unroll
          for (int r = 0; r < 4; ++r) pk[r] = f32_to_bf16(acc[mi][ni][r] + bb);
          *(u16x4*)(VT + d * 136 + wm * 64 + mi * 16 + quad * 4) = pk;
        }
      }
    }
    __syncthreads();
    // cooperative coalesced store of VT -> outV [bh][d][sx]
    {
      const int d = tid >> 2, ch = tid & 3;
      u16* dst = outV + (((size_t)(b * 16 + h) * 64 + d) * 2048 + sx0 + ch * 32);
      const u16* src = VT + d * 136 + ch * 32;
#pragma unroll
      for (int i = 0; i < 4; ++i)
        *(u16x8*)(dst + i * 8) = *(const u16x8*)(src + i * 8);
    }
  } else {
#pragma unroll
    for (int ni = 0; ni < 4; ++ni) {
      const int n = tn * 128 + wn * 64 + ni * 16 + l15;
      const float bb = bias[n];
#pragma unroll
      for (int mi = 0; mi < 4; ++mi) {
#pragma unroll
        for (int r = 0; r < 4; ++r) {
          const int m = tm * 128 + wm * 64 + mi * 16 + quad * 4 + r;
          outF[(size_t)m * 1024 + n] = acc[mi][ni][r] + bb;
        }
      }
    }
  }
}

// ---------------------------------------------------------------------------
// flash attention v8: REVERT to the R2-verified 128-kv-tile structure
// (counted-vmcnt pipeline regressed: at ~3-5 blocks/CU, cross-block wave
// overlap already hides the stage drain; the pipeline only doubled the
// barrier count — m114/m99 regime). Single 32KB buffer set, 2 barriers
// per 128-kv tile. P in-register (cvt_pk + permlane), l via mfma(ap,1),
// setprio around MFMA clusters.
// NEW vs R2: Q read directly from the f32 input (scale+pack in prologue,
// once per block) — kills the q half of cvt_cq and the qh workspace.
// ---------------------------------------------------------------------------
__global__ __launch_bounds__(256, 5) void flash_kernel(
    const float* __restrict__ Qf,  // [B,2048,1024] f32 (pre-projected q)
    const u16* __restrict__ Kp,    // [BH,2048,64] bf16
    const u16* __restrict__ Vt,    // [BH,64,2048] bf16
    u16* __restrict__ Opk) {       // [B,2048,1024] bf16
  __shared__ __align__(16) u16 Ks[128 * 64];
  __shared__ __align__(16) u16 Vts[64 * 128];

  const int tid = threadIdx.x;
  const int lane = tid & 63, w = tid >> 6, quad = lane >> 4, l15 = lane & 15;
  // XCD-swizzled mapping: same bh stays on one XCD (L2 K/V reuse)
  const int id = blockIdx.x;
  const int bh = (id & 7) + 8 * (id >> 8);
  const int qt = (id >> 3) & 31;
  const int q0 = qt * 64;
  const int b = bh >> 4, h = bh & 15;

  const u16* kbase = Kp + (size_t)bh * 2048 * 64;
  const u16* vbase = Vt + (size_t)bh * 64 * 2048;

  // Q B-fragments from f32 global, scaled by 0.125*log2(e), packed to bf16.
  // B[n=q][k=d]: n = l15 (q row within 16), k = quad*8+j.
  const float SC = 0.125f * 1.44269504088896f;
  const float* qrow = Qf + ((size_t)(b * 2048 + q0 + w * 16 + l15)) * 1024 + h * 64;
  f32x4 qa = *(const f32x4*)(qrow + quad * 8);
  f32x4 qb = *(const f32x4*)(qrow + quad * 8 + 4);
  f32x4 qc = *(const f32x4*)(qrow + 32 + quad * 8);
  f32x4 qd = *(const f32x4*)(qrow + 32 + quad * 8 + 4);
  union { unsigned int u[4]; bf16x8 v; } Q0, Q1;
  Q0.u[0] = cvt_pk_bf16(qa[0] * SC, qa[1] * SC);
  Q0.u[1] = cvt_pk_bf16(qa[2] * SC, qa[3] * SC);
  Q0.u[2] = cvt_pk_bf16(qb[0] * SC, qb[1] * SC);
  Q0.u[3] = cvt_pk_bf16(qb[2] * SC, qb[3] * SC);
  Q1.u[0] = cvt_pk_bf16(qc[0] * SC, qc[1] * SC);
  Q1.u[1] = cvt_pk_bf16(qc[2] * SC, qc[3] * SC);
  Q1.u[2] = cvt_pk_bf16(qd[0] * SC, qd[1] * SC);
  Q1.u[3] = cvt_pk_bf16(qd[2] * SC, qd[3] * SC);
  bf16x8 bq0 = Q0.v;
  bf16x8 bq1 = Q1.v;

  // all-ones bf16 B-fragment for the l-sum MFMA (B[n][k] = 1.0)
  bf16x8 ones;
#pragma unroll
  for (int i = 0; i < 8; ++i) ones[i] = (__bf16)1.0f;

  const f32x4 zero4 = {0.f, 0.f, 0.f, 0.f};
  f32x4 oacc[4];
  f32x4 lacc = zero4;
#pragma unroll
  for (int di = 0; di < 4; ++di) oacc[di] = zero4;

  for (int t = 0; t < 16; ++t) {
    const int kv0 = t * 128;
#pragma unroll
    for (int p = 0; p < 4; ++p) {
      int l = p * 256 + tid;
      int kv = l >> 3, dc = l & 7;
      load_lds16(kbase + (kv0 + kv) * 64 + ((dc ^ (kv & 7)) * 8), Ks + (p * 256 + (tid & 192)) * 8);
    }
#pragma unroll
    for (int p = 0; p < 4; ++p) {
      int l = p * 256 + tid;
      int d = l >> 4, dc = l & 15;
      load_lds16(vbase + (size_t)d * 2048 + kv0 + ((dc ^ (d & 15)) * 8),
                 Vts + (p * 256 + (tid & 192)) * 8);
    }
    __syncthreads();

#pragma unroll
    for (int c = 0; c < 4; ++c) {
      // S^T chunk: 32 kv rows x 16 q cols per wave (A = K frag, B = Q frag)
      f32x4 s0 = zero4, s1 = zero4;
      {
        const int sw0 = (quad ^ (l15 & 7)) * 8;
        bf16x8 ak0 = *(const bf16x8*)(Ks + ((c * 2 + 0) * 16 + l15) * 64 + sw0);
        bf16x8 ak1 = *(const bf16x8*)(Ks + ((c * 2 + 1) * 16 + l15) * 64 + sw0);
        const int sw1 = ((4 + quad) ^ (l15 & 7)) * 8;
        bf16x8 ak2 = *(const bf16x8*)(Ks + ((c * 2 + 0) * 16 + l15) * 64 + sw1);
        bf16x8 ak3 = *(const bf16x8*)(Ks + ((c * 2 + 1) * 16 + l15) * 64 + sw1);
        __builtin_amdgcn_s_setprio(1);
        s0 = __builtin_amdgcn_mfma_f32_16x16x32_bf16(ak0, bq0, s0, 0, 0, 0);
        s1 = __builtin_amdgcn_mfma_f32_16x16x32_bf16(ak1, bq0, s1, 0, 0, 0);
        s0 = __builtin_amdgcn_mfma_f32_16x16x32_bf16(ak2, bq1, s0, 0, 0, 0);
        s1 = __builtin_amdgcn_mfma_f32_16x16x32_bf16(ak3, bq1, s1, 0, 0, 0);
        __builtin_amdgcn_s_setprio(0);
      }

      // p = exp2(s), pack to bf16 pairs (1 VALU op per pair)
      f32x4 pv0, pv1;
#pragma unroll
      for (int r = 0; r < 4; ++r) {
        pv0[r] = __builtin_amdgcn_exp2f(s0[r]);
        pv1[r] = __builtin_amdgcn_exp2f(s1[r]);
      }
      unsigned int a0 = cvt_pk_bf16(pv0[0], pv0[1]);   // kv = qd*4+0,+1   (s0)
      unsigned int a1 = cvt_pk_bf16(pv0[2], pv0[3]);   // kv = qd*4+2,+3   (s0)
      unsigned int b0 = cvt_pk_bf16(pv1[0], pv1[1]);   // kv = 16+qd*4+0,+1 (s1)
      unsigned int b1 = cvt_pk_bf16(pv1[2], pv1[3]);   // kv = 16+qd*4+2,+3 (s1)

      // cross-quad redistribute: lane (l15,quad) ends with kv = quad*8..+7.
      u32x2 t0 = __builtin_amdgcn_permlane32_swap(a0, b0, false, false);
      u32x2 t1 = __builtin_amdgcn_permlane32_swap(a1, b1, false, false);
      u32x2 u0 = __builtin_amdgcn_permlane16_swap(t0.x, t0.y, false, false);
      u32x2 u1 = __builtin_amdgcn_permlane16_swap(t1.x, t1.y, false, false);

      union { unsigned int u[4]; bf16x8 v; } P;
      P.u[0] = u0.x;   // kv pairs (8t+0,1)
      P.u[1] = u1.x;   // kv pairs (8t+2,3)
      P.u[2] = u0.y;   // kv pairs (8t+4,5)
      P.u[3] = u1.y;   // kv pairs (8t+6,7)
      bf16x8 ap = P.v;

      // O += P V for this 32-kv chunk; l += P·1 on the same pipe
      bf16x8 bv0 = *(const bf16x8*)(Vts + (0 * 16 + l15) * 128 + (((c * 4 + quad) ^ l15) * 8));
      bf16x8 bv1 = *(const bf16x8*)(Vts + (1 * 16 + l15) * 128 + (((c * 4 + quad) ^ l15) * 8));
      bf16x8 bv2 = *(const bf16x8*)(Vts + (2 * 16 + l15) * 128 + (((c * 4 + quad) ^ l15) * 8));
      bf16x8 bv3 = *(const bf16x8*)(Vts + (3 * 16 + l15) * 128 + (((c * 4 + quad) ^ l15) * 8));
      __builtin_amdgcn_s_setprio(1);
      oacc[0] = __builtin_amdgcn_mfma_f32_16x16x32_bf16(ap, bv0, oacc[0], 0, 0, 0);
      oacc[1] = __builtin_amdgcn_mfma_f32_16x16x32_bf16(ap, bv1, oacc[1], 0, 0, 0);
      oacc[2] = __builtin_amdgcn_mfma_f32_16x16x32_bf16(ap, bv2, oacc[2], 0, 0, 0);
      oacc[3] = __builtin_amdgcn_mfma_f32_16x16x32_bf16(ap, bv3, oacc[3], 0, 0, 0);
      lacc = __builtin_amdgcn_mfma_f32_16x16x32_bf16(ap, ones, lacc, 0, 0, 0);
      __builtin_amdgcn_s_setprio(0);
    }
    __syncthreads();
  }

  // epilogue: normalize, write [B,S,1024] bf16.
  // lacc C-layout: row = quad*4+r = q (mod 16), col = l15 (all cols equal)
  // -> linv for row quad*4+r is simply 1/lacc[r]; no cross-lane reduction.
#pragma unroll
  for (int r = 0; r < 4; ++r) {
    float linv = 1.0f / lacc[r];
    int row = q0 + w * 16 + quad * 4 + r;
    u16* dst = Opk + ((size_t)(b * 2048 + row)) * 1024 + h * 64;
#pragma unroll
    for (int di = 0; di < 4; ++di)
      dst[di * 16 + l15] = f32_to_bf16(oacc[di][r] * linv);
  }
}

// ---------------------------------------------------------------------------

extern "C" void kernel_launch(void* const* d_in, const int* in_sizes, int n_in,
                              void* d_out, int out_size, void* d_ws, size_t ws_size,
                              hipStream_t stream) {
  const float* q   = (const float*)d_in[0];
  const float* c   = (const float*)d_in[1];
  const float* Wkv = (const float*)d_in[2];
  const float* bkv = (const float*)d_in[3];
  const float* Wo  = (const float*)d_in[4];
  const float* bo  = (const float*)d_in[5];
  float* out = (float*)d_out;
  char* ws = (char*)d_ws;

  u16* c_bf = (u16*)(ws + 0);          // 16 MB  [8192,1024] bf16
  u16* Wkvt = (u16*)(ws + 33554432);   //  4 MB  [2048,1024]
  u16* Wot  = (u16*)(ws + 37748736);   //  2 MB  [1024,1024]
  u16* KpB  = (u16*)(ws + 39845888);   // 16 MB  [64,2048,64]
  u16* VtB  = (u16*)(ws + 56623104);   // 16 MB  [64,64,2048]
  u16* Opk  = c_bf;                    // reuse: c_bf dead after gemm<0>

  cvt_cq_kernel<<<4096, 256, 0, stream>>>(c, c_bf);
  transpose_w_kernel<<<dim3(32, 16), 256, 0, stream>>>(Wkv, Wkvt, 2048);
  transpose_w_kernel<<<dim3(16, 16), 256, 0, stream>>>(Wo, Wot, 1024);
  gemm128<0><<<dim3(16, 64), 256, 0, stream>>>(c_bf, Wkvt, bkv, KpB, VtB, nullptr, 1024);
  flash_kernel<<<2048, 256, 0, stream>>>(q, KpB, VtB, Opk);
  gemm128<1><<<dim3(8, 64), 256, 0, stream>>>(Opk, Wot, bo, nullptr, nullptr, out, 1024);
}